// Round 9
// baseline (8368.967 us; speedup 1.0000x reference)
//
#include <hip/hip_runtime.h>
#include <hip/hip_bf16.h>

// CustomLSTMModel: emb(32000x300 fp32, pad_idx=0) -> LSTM(300->512, 512 steps, B=256, fp32)
//                  -> FC(512->7, fp32). tokens int32; out fp32 [256,7].
// Internal: bf16 MFMA (RNE), fp32 accum/c/biases/FC. absmax ~1e-3 (R2..R8: 9.8e-4).
//
// R9 vs R8 (2.37 ms; latency-chain-bound: MfmaUtil 8%, VALUBusy 12% -> 80% idle-wait):
//  - NO LDS h-staging: hh B-frags loaded DIRECTLY global->VGPR (per lane 2 u64
//    bypassing loads per chunk; 4 chunks batched per round so LLC latency pipelines).
//    Deletes S2a/S2b barriers + LDS round-trip from the serial chain.
//  - Per-wave autonomy: every wave polls the 128 per-wave flags itself (64 lanes x
//    u64); producers publish per-wave after own vmcnt drain. No block-wide coupling
//    for h at all.
//  - x panel double-buffered in LDS -> exactly ONE barrier per step
//    (A: ih reads xb[p]; C: write xb[1-p]; B: barrier; D: poll+direct-load+hh;
//    E/F: elementwise+pack+store+drain+publish; G: prefetch).  Race-free: reads of
//    xb[p] all precede B(t); writes of xb[p] next occur in C(t+1) after B(t).
// Carried: relaxed agent atomics only (LLC-coherent, no fences/wbl2); W+c in VGPRs;
// x VGPR prefetch (R6); 8 groups x 16 blocks x 512 thr; group = bid&7.
// Known risk: 8 waves x 32KB/step redundant LLC reads (~4MB/group/step) may bind LLC BW.

typedef unsigned short ushort_t;
typedef unsigned long long u64_t;
typedef __bf16 bf16x8 __attribute__((ext_vector_type(8)));
typedef unsigned short u16x8v __attribute__((ext_vector_type(8)));
typedef float f32x4 __attribute__((ext_vector_type(4)));
typedef u64_t u64x2 __attribute__((ext_vector_type(2)));

#define XSTRIDE 328   // ushorts per x row (320 data + 8 pad); 656B, 16B-aligned
#define XHALF (32 * XSTRIDE)

__device__ __forceinline__ float sigmoidf_(float x) { return 1.0f / (1.0f + __expf(-x)); }
__device__ __forceinline__ float tanhf_(float x)    { return 1.0f - 2.0f / (__expf(2.0f * x) + 1.0f); }

__device__ __forceinline__ ushort_t f2bf(float f) {   // RNE; inputs finite
    unsigned u = __builtin_bit_cast(unsigned, f);
    unsigned r = (u + 0x7FFFu + ((u >> 16) & 1u)) >> 16;
    return (ushort_t)r;
}
__device__ __forceinline__ float bf2f(ushort_t u) {
    unsigned v = ((unsigned)u) << 16;
    return __builtin_bit_cast(float, v);
}

// LLC-coherent (cache-bypassing) accessors — relaxed agent atomics, no fences.
__device__ __forceinline__ u64_t g_load64(const u64_t* p) {
    return __hip_atomic_load(p, __ATOMIC_RELAXED, __HIP_MEMORY_SCOPE_AGENT);
}
__device__ __forceinline__ void g_store64(u64_t* p, u64_t v) {
    __hip_atomic_store(p, v, __ATOMIC_RELAXED, __HIP_MEMORY_SCOPE_AGENT);
}
__device__ __forceinline__ void g_store_flag(int* p, int v) {
    __hip_atomic_store(p, v, __ATOMIC_RELAXED, __HIP_MEMORY_SCOPE_AGENT);
}

__global__ __launch_bounds__(512, 2)
void lstm_fused_kernel(const int* __restrict__ tokens,    // [256][512]
                       const float* __restrict__ emb,     // [32000][300]
                       const float* __restrict__ Wih,     // [2048][300]
                       const float* __restrict__ bih,     // [2048]
                       const float* __restrict__ Whh,     // [2048][512]
                       const float* __restrict__ bhh,     // [2048]
                       const float* __restrict__ Wfc,     // [7][512]
                       const float* __restrict__ bfc,     // [7]
                       float* __restrict__ out,           // [256][7]
                       int* __restrict__ flags,           // [1024]: 128 per group
                       ushort_t* __restrict__ hbuf)       // [2][256][512] bf16
{
    __shared__ ushort_t xb_lds[2 * XHALF];   // 41984 B: x double buffer

    const int tid = threadIdx.x;
    const int bid = blockIdx.x;
    const int g   = bid & 7;       // batch group 0..7 (XCD-aligned round-robin)
    const int ib  = bid >> 3;      // block-in-group 0..15 -> unit slice
    const int Bg0 = g * 32;
    const int U0  = ib * 32;       // 32 units per block
    const int lane = tid & 63;
    const int wv   = tid >> 6;     // wave 0..7 = M-tile (16 gate rows; units U0+4wv+q)
    const int lm   = lane & 15;
    const int q    = lane >> 4;

    // ---- preload A-fragments (R7 layout), fp32 -> bf16 RNE (once) ----
    bf16x8 aih[10];
    bf16x8 ahh[16];
    {
        const int rp   = 16 * wv + lm;          // row in block's 128 (unit_local*4 + gate)
        const int gi   = rp & 3;
        const int up   = rp >> 2;               // unit_local 0..31
        const int grow = gi * 512 + U0 + up;    // global gate row
#pragma unroll
        for (int kc = 0; kc < 10; ++kc) {
            u16x8v tmp;
#pragma unroll
            for (int j = 0; j < 8; ++j) {
                int col = 32 * kc + 8 * q + j;
                tmp[j] = (col < 300) ? f2bf(Wih[grow * 300 + col]) : (ushort_t)0;
            }
            aih[kc] = __builtin_bit_cast(bf16x8, tmp);
        }
#pragma unroll
        for (int kc = 0; kc < 16; ++kc) {
            u16x8v tmp;
#pragma unroll
            for (int j = 0; j < 8; ++j) {
                int col = 32 * kc + 8 * q + j;
                tmp[j] = f2bf(Whh[grow * 512 + col]);
            }
            ahh[kc] = __builtin_bit_cast(bf16x8, tmp);
        }
    }

    // ---- per-lane biases: unit = U0 + 4*wv + q; acc comps = gates i,f,g,o ----
    float bias0, bias1, bias2, bias3;
    {
        const int unit = U0 + 4 * wv + q;
        bias0 = bih[0 * 512 + unit] + bhh[0 * 512 + unit];
        bias1 = bih[1 * 512 + unit] + bhh[1 * 512 + unit];
        bias2 = bih[2 * 512 + unit] + bhh[2 * 512 + unit];
        bias3 = bih[3 * 512 + unit] + bhh[3 * 512 + unit];
    }

    // ---- init: zero h parity-0 (h0=0), publish 8 per-wave flags = 1 ----
    if (tid < 256) {
        int r = tid >> 3;
        int d = tid & 7;
        g_store64((u64_t*)(hbuf + (size_t)(Bg0 + r) * 512 + U0 + 4 * d), 0ull);
    }
    __syncthreads();             // drains init stores
    if (tid < 8) g_store_flag(&flags[g * 128 + ib * 8 + tid], 1);

    const u64_t* fl2 = (const u64_t*)&flags[g * 128 + 2 * lane];  // 64 lanes x 2 flags = 128
    int* mypub = &flags[g * 128 + ib * 8 + wv];

    float cA = 0.0f, cB = 0.0f;

    // ---- x prefetch state: thread covers row xr, dwords xln+16k ----
    const int xr  = tid >> 4;
    const int xln = tid & 15;
    const int xb  = Bg0 + xr;
    int tok_cur, tok_nxt;
    float2 xp[10];
    {
        int tk0 = tokens[xb * 512 + 0];
        const float2* s2 = (const float2*)(emb + (size_t)tk0 * 300);
        unsigned int* dstx = (unsigned int*)(xb_lds + xr * XSTRIDE);
        const bool tz = (tk0 != 0);
#pragma unroll
        for (int k = 0; k < 10; ++k) {
            int i = xln + 16 * k;
            unsigned int v = 0u;
            if (tz && i < 150) {
                float2 p = s2[i];
                v = (unsigned int)f2bf(p.x) | ((unsigned int)f2bf(p.y) << 16);
            }
            dstx[i] = v;
        }
        tok_cur = tokens[xb * 512 + 1];
        const float2* s2n = (const float2*)(emb + (size_t)tok_cur * 300);
#pragma unroll
        for (int k = 0; k < 10; ++k) {
            int i = xln + 16 * k;
            if (i < 150) xp[k] = s2n[i];
        }
        tok_nxt = tokens[xb * 512 + 2];
    }
    __syncthreads();   // x_0 staged in xb_lds[0]

    for (int t = 0; t < 512; ++t) {
        // ---- A. ih-MFMAs from x parity buffer ----
        f32x4 acc0 = {0.f, 0.f, 0.f, 0.f};
        f32x4 acc1 = {0.f, 0.f, 0.f, 0.f};
        {
            const ushort_t* u0 = xb_lds + (t & 1) * XHALF + lm * XSTRIDE + 8 * q;
            const ushort_t* u1 = u0 + 16 * XSTRIDE;
#pragma unroll
            for (int kc = 0; kc < 10; ++kc) {
                bf16x8 b0 = __builtin_bit_cast(bf16x8, *(const u16x8v*)(u0 + 32 * kc));
                bf16x8 b1 = __builtin_bit_cast(bf16x8, *(const u16x8v*)(u1 + 32 * kc));
                acc0 = __builtin_amdgcn_mfma_f32_16x16x32_bf16(aih[kc], b0, acc0, 0, 0, 0);
                acc1 = __builtin_amdgcn_mfma_f32_16x16x32_bf16(aih[kc], b1, acc1, 0, 0, 0);
            }
        }

        // ---- C. consume xp -> other x parity buffer (disjoint from A's reads) ----
        {
            unsigned int* dstx = (unsigned int*)(xb_lds + ((t + 1) & 1) * XHALF + xr * XSTRIDE);
            const bool tz = (tok_cur != 0);
#pragma unroll
            for (int k = 0; k < 10; ++k) {
                int i = xln + 16 * k;
                unsigned int v = 0u;
                if (tz && i < 150)
                    v = (unsigned int)f2bf(xp[k].x) | ((unsigned int)f2bf(xp[k].y) << 16);
                dstx[i] = v;
            }
        }
        __syncthreads();   // the ONLY barrier: x_{t+1} staged; x_t reads all done

        // ---- D. per-wave: poll all 128 flags, then direct-load hh B-frags + MFMA ----
        {
            const int target = t + 1;
            while (true) {
                u64_t v2 = g_load64(fl2);
                int lo = (int)(unsigned)(v2 & 0xffffffffull);
                int hi = (int)(unsigned)(v2 >> 32);
                if (__all(lo >= target && hi >= target)) break;
                __builtin_amdgcn_s_sleep(1);
            }
            asm volatile("" ::: "memory");
        }
        {
            const ushort_t* hb = hbuf + (size_t)(t & 1) * (256 * 512);
            const ushort_t* r0 = hb + (size_t)(Bg0 + lm) * 512 + 8 * q;
            const ushort_t* r1 = hb + (size_t)(Bg0 + 16 + lm) * 512 + 8 * q;
#pragma unroll
            for (int r = 0; r < 4; ++r) {
                bf16x8 b0[4], b1[4];
#pragma unroll
                for (int i = 0; i < 4; ++i) {
                    const int j = 4 * r + i;
                    u64x2 t0, t1;
                    t0.x = g_load64((const u64_t*)(r0 + 32 * j));
                    t0.y = g_load64((const u64_t*)(r0 + 32 * j + 4));
                    t1.x = g_load64((const u64_t*)(r1 + 32 * j));
                    t1.y = g_load64((const u64_t*)(r1 + 32 * j + 4));
                    b0[i] = __builtin_bit_cast(bf16x8, t0);
                    b1[i] = __builtin_bit_cast(bf16x8, t1);
                }
#pragma unroll
                for (int i = 0; i < 4; ++i) {
                    const int j = 4 * r + i;
                    acc0 = __builtin_amdgcn_mfma_f32_16x16x32_bf16(ahh[j], b0[i], acc0, 0, 0, 0);
                    acc1 = __builtin_amdgcn_mfma_f32_16x16x32_bf16(ahh[j], b1[i], acc1, 0, 0, 0);
                }
            }
        }

        // ---- E. elementwise LSTM + shfl-pack; F. per-wave store + drain + publish ----
        {
            float ig = sigmoidf_(acc0.x + bias0);
            float fg = sigmoidf_(acc0.y + bias1);
            float gg = tanhf_(acc0.z + bias2);
            float og = sigmoidf_(acc0.w + bias3);
            cA = fg * cA + ig * gg;
            unsigned pA = f2bf(og * tanhf_(cA));

            ig = sigmoidf_(acc1.x + bias0);
            fg = sigmoidf_(acc1.y + bias1);
            gg = tanhf_(acc1.z + bias2);
            og = sigmoidf_(acc1.w + bias3);
            cB = fg * cB + ig * gg;
            unsigned pB = f2bf(og * tanhf_(cB));

            unsigned a0 = (unsigned)__shfl((int)pA, lm);
            unsigned a1 = (unsigned)__shfl((int)pA, lm + 16);
            unsigned a2 = (unsigned)__shfl((int)pA, lm + 32);
            unsigned a3 = (unsigned)__shfl((int)pA, lm + 48);
            unsigned b0 = (unsigned)__shfl((int)pB, lm);
            unsigned b1 = (unsigned)__shfl((int)pB, lm + 16);
            unsigned b2 = (unsigned)__shfl((int)pB, lm + 32);
            unsigned b3 = (unsigned)__shfl((int)pB, lm + 48);
            u64_t uA = (u64_t)(a0 | (a1 << 16)) | ((u64_t)(a2 | (a3 << 16)) << 32);
            u64_t uB = (u64_t)(b0 | (b1 << 16)) | ((u64_t)(b2 | (b3 << 16)) << 32);

            ushort_t* hdst = hbuf + (size_t)((t + 1) & 1) * (256 * 512);
            if (q == 0)
                g_store64((u64_t*)(hdst + (size_t)(Bg0 + lm) * 512 + U0 + 4 * wv), uA);
            else if (q == 1)
                g_store64((u64_t*)(hdst + (size_t)(Bg0 + 16 + lm) * 512 + U0 + 4 * wv), uB);
        }
        asm volatile("s_waitcnt vmcnt(0)" ::: "memory");   // own h stores at LLC
        if (lane == 0) g_store_flag(mypub, t + 2);

        // ---- G. issue x prefetch for t+2 (after drain: stays in flight) ----
        {
            tok_cur = tok_nxt;
            const float2* s2 = (const float2*)(emb + (size_t)tok_cur * 300);
#pragma unroll
            for (int k = 0; k < 10; ++k) {
                int i = xln + 16 * k;
                if (i < 150) xp[k] = s2[i];
            }
            int t3 = (t + 3 < 512) ? (t + 3) : 511;
            tok_nxt = tokens[xb * 512 + t3];
        }
    }

    // ---- epilogue: every wave waits group done (513), then FC ----
    {
        while (true) {
            u64_t v2 = g_load64(fl2);
            int lo = (int)(unsigned)(v2 & 0xffffffffull);
            int hi = (int)(unsigned)(v2 >> 32);
            if (__all(lo >= 513 && hi >= 513)) break;
            __builtin_amdgcn_s_sleep(1);
        }
        asm volatile("" ::: "memory");
    }

    {
        const int bb = Bg0 + 2 * ib + (wv & 1);
        const int obase = wv >> 1;                       // 0..3
        const ushort_t* hrow = hbuf + (size_t)bb * 512;  // final h in parity 0
        u64_t h0 = g_load64((const u64_t*)(hrow + lane * 8));
        u64_t h1 = g_load64((const u64_t*)(hrow + lane * 8 + 4));
        float hv[8];
#pragma unroll
        for (int j = 0; j < 4; ++j) hv[j]     = bf2f((ushort_t)(h0 >> (16 * j)));
#pragma unroll
        for (int j = 0; j < 4; ++j) hv[4 + j] = bf2f((ushort_t)(h1 >> (16 * j)));
#pragma unroll
        for (int oo = 0; oo < 2; ++oo) {
            int o = obase + oo * 4;
            if (o < 7) {
                f32x4 w0 = *(const f32x4*)(Wfc + o * 512 + lane * 8);
                f32x4 w1 = *(const f32x4*)(Wfc + o * 512 + lane * 8 + 4);
                float s = hv[0] * w0.x + hv[1] * w0.y + hv[2] * w0.z + hv[3] * w0.w
                        + hv[4] * w1.x + hv[5] * w1.y + hv[6] * w1.z + hv[7] * w1.w;
#pragma unroll
                for (int sh = 32; sh >= 1; sh >>= 1) s += __shfl_down(s, sh);
                if (lane == 0)
                    out[bb * 7 + o] = s + bfc[o];
            }
        }
    }
}

extern "C" void kernel_launch(void* const* d_in, const int* in_sizes, int n_in,
                              void* d_out, int out_size, void* d_ws, size_t ws_size,
                              hipStream_t stream) {
    const int* tokens = (const int*)d_in[0];
    const float* emb  = (const float*)d_in[1];
    const float* Wih  = (const float*)d_in[2];
    const float* bih  = (const float*)d_in[3];
    const float* Whh  = (const float*)d_in[4];
    const float* bhh  = (const float*)d_in[5];
    const float* Wfc  = (const float*)d_in[6];
    const float* bfc  = (const float*)d_in[7];

    int* flags      = (int*)d_ws;                       // 1024 ints: 128 per group
    ushort_t* hbuf  = (ushort_t*)((char*)d_ws + 4096);  // [2][256][512] bf16 = 512 KiB

    lstm_fused_kernel<<<dim3(128), dim3(512), 0, stream>>>(
        tokens, emb, Wih, bih, Whh, bhh, Wfc, bfc,
        (float*)d_out, flags, hbuf);
}

// Round 10
// 2266.448 us; speedup vs baseline: 3.6925x; 3.6925x over previous
//
#include <hip/hip_runtime.h>
#include <hip/hip_bf16.h>

// CustomLSTMModel: emb(32000x300 fp32, pad_idx=0) -> LSTM(300->512, 512 steps, B=256, fp32)
//                  -> FC(512->7, fp32). tokens int32; out fp32 [256,7].
// Internal: bf16 MFMA (RNE), fp32 accum/c/biases/FC. absmax ~1e-3 (R2..R9: 9.8e-4).
//
// R10 = R7 (best proven structure, 2.16ms) + sync-overhead cuts. R9 lesson burned in:
// bypassing h traffic MUST be block-staged+coalesced through LDS (per-wave direct
// global loads = 16x LLC transactions = 4x slowdown). R8 lesson: LDS conflicts and
// K-splitting are off the critical path. R5 lesson: store coalescing off-path.
//  - x double-buffer in LDS (from R9, the one good piece): removes loop-end barrier.
//    2 barriers/step: S2a (poll release), S2b (h staged). Race-free: A(t+1) reads
//    parity p after S2a(t); C(t) wrote parity p' (disjoint); C(t+1) writes p after
//    S2b(t).
//  - PADDED FLAGS: one 64B sector per producer flag (128/group x 64B). Producer
//    flag stores no longer queue behind pollers' reads on shared hot lines.
// Carried: relaxed agent atomics only (no fences/wbl2 - R4); coalesced LDS h staging
// (R4); per-wave publish after own vmcnt drain (R7); x VGPR prefetch 1 step deep
// (R6); W+c in VGPRs; 8 groups x 16 blocks x 512 thr; group = bid&7.

typedef unsigned short ushort_t;
typedef unsigned long long u64_t;
typedef __bf16 bf16x8 __attribute__((ext_vector_type(8)));
typedef unsigned short u16x8v __attribute__((ext_vector_type(8)));
typedef float f32x4 __attribute__((ext_vector_type(4)));

#define XSTRIDE 328           // ushorts per x row (320 data + 8 pad)
#define XHALF (32 * XSTRIDE)  // one x parity panel
#define HSTRIDE 520           // ushorts per h row (512 + 8 pad)
#define FSTR 16               // ints per flag slot = 64B sector

__device__ __forceinline__ float sigmoidf_(float x) { return 1.0f / (1.0f + __expf(-x)); }
__device__ __forceinline__ float tanhf_(float x)    { return 1.0f - 2.0f / (__expf(2.0f * x) + 1.0f); }

__device__ __forceinline__ ushort_t f2bf(float f) {   // RNE; inputs finite
    unsigned u = __builtin_bit_cast(unsigned, f);
    unsigned r = (u + 0x7FFFu + ((u >> 16) & 1u)) >> 16;
    return (ushort_t)r;
}
__device__ __forceinline__ float bf2f(ushort_t u) {
    unsigned v = ((unsigned)u) << 16;
    return __builtin_bit_cast(float, v);
}

// LLC-coherent (cache-bypassing) accessors — relaxed agent atomics, no fences.
__device__ __forceinline__ u64_t g_load64(const u64_t* p) {
    return __hip_atomic_load(p, __ATOMIC_RELAXED, __HIP_MEMORY_SCOPE_AGENT);
}
__device__ __forceinline__ void g_store64(u64_t* p, u64_t v) {
    __hip_atomic_store(p, v, __ATOMIC_RELAXED, __HIP_MEMORY_SCOPE_AGENT);
}
__device__ __forceinline__ int g_load_flag(const int* p) {
    return __hip_atomic_load(p, __ATOMIC_RELAXED, __HIP_MEMORY_SCOPE_AGENT);
}
__device__ __forceinline__ void g_store_flag(int* p, int v) {
    __hip_atomic_store(p, v, __ATOMIC_RELAXED, __HIP_MEMORY_SCOPE_AGENT);
}

__global__ __launch_bounds__(512, 2)
void lstm_fused_kernel(const int* __restrict__ tokens,    // [256][512]
                       const float* __restrict__ emb,     // [32000][300]
                       const float* __restrict__ Wih,     // [2048][300]
                       const float* __restrict__ bih,     // [2048]
                       const float* __restrict__ Whh,     // [2048][512]
                       const float* __restrict__ bhh,     // [2048]
                       const float* __restrict__ Wfc,     // [7][512]
                       const float* __restrict__ bfc,     // [7]
                       float* __restrict__ out,           // [256][7]
                       int* __restrict__ flags,           // [1024*FSTR] padded
                       ushort_t* __restrict__ hbuf)       // [2][256][512] bf16
{
    __shared__ ushort_t xb_lds[2 * XHALF];      // 41984 B: x double buffer
    __shared__ ushort_t h_lds[32 * HSTRIDE];    // 33280 B: h panel

    const int tid = threadIdx.x;
    const int bid = blockIdx.x;
    const int g   = bid & 7;       // batch group 0..7 (XCD-aligned round-robin)
    const int ib  = bid >> 3;      // block-in-group 0..15 -> unit slice
    const int Bg0 = g * 32;
    const int U0  = ib * 32;       // 32 units per block
    const int lane = tid & 63;
    const int wv   = tid >> 6;     // wave 0..7 = M-tile (16 gate rows; units U0+4wv+q)
    const int lm   = lane & 15;
    const int q    = lane >> 4;

    // ---- preload A-fragments (R7 layout), fp32 -> bf16 RNE (once) ----
    bf16x8 aih[10];
    bf16x8 ahh[16];
    {
        const int rp   = 16 * wv + lm;          // row in block's 128 (unit_local*4 + gate)
        const int gi   = rp & 3;
        const int up   = rp >> 2;               // unit_local 0..31
        const int grow = gi * 512 + U0 + up;    // global gate row
#pragma unroll
        for (int kc = 0; kc < 10; ++kc) {
            u16x8v tmp;
#pragma unroll
            for (int j = 0; j < 8; ++j) {
                int col = 32 * kc + 8 * q + j;
                tmp[j] = (col < 300) ? f2bf(Wih[grow * 300 + col]) : (ushort_t)0;
            }
            aih[kc] = __builtin_bit_cast(bf16x8, tmp);
        }
#pragma unroll
        for (int kc = 0; kc < 16; ++kc) {
            u16x8v tmp;
#pragma unroll
            for (int j = 0; j < 8; ++j) {
                int col = 32 * kc + 8 * q + j;
                tmp[j] = f2bf(Whh[grow * 512 + col]);
            }
            ahh[kc] = __builtin_bit_cast(bf16x8, tmp);
        }
    }

    // ---- per-lane biases: unit = U0 + 4*wv + q; acc comps = gates i,f,g,o ----
    float bias0, bias1, bias2, bias3;
    {
        const int unit = U0 + 4 * wv + q;
        bias0 = bih[0 * 512 + unit] + bhh[0 * 512 + unit];
        bias1 = bih[1 * 512 + unit] + bhh[1 * 512 + unit];
        bias2 = bih[2 * 512 + unit] + bhh[2 * 512 + unit];
        bias3 = bih[3 * 512 + unit] + bhh[3 * 512 + unit];
    }

    // ---- init: zero h parity-0 (h0=0), publish 8 per-wave flags = 1 ----
    if (tid < 256) {
        int r = tid >> 3;
        int d = tid & 7;
        g_store64((u64_t*)(hbuf + (size_t)(Bg0 + r) * 512 + U0 + 4 * d), 0ull);
    }
    __syncthreads();             // drains init stores
    int* fb = flags + g * 128 * FSTR;
    if (tid < 8) g_store_flag(fb + (ib * 8 + tid) * FSTR, 1);
    int* mypub = fb + (ib * 8 + wv) * FSTR;

    float cA = 0.0f, cB = 0.0f;

    // ---- x prefetch state: thread covers row xr, dwords xln+16k ----
    const int xr  = tid >> 4;
    const int xln = tid & 15;
    const int xb  = Bg0 + xr;
    int tok_cur, tok_nxt;
    float2 xp[10];
    {
        int tk0 = tokens[xb * 512 + 0];
        const float2* s2 = (const float2*)(emb + (size_t)tk0 * 300);
        unsigned int* dstx = (unsigned int*)(xb_lds + xr * XSTRIDE);
        const bool tz = (tk0 != 0);
#pragma unroll
        for (int k = 0; k < 10; ++k) {
            int i = xln + 16 * k;
            unsigned int v = 0u;
            if (tz && i < 150) {
                float2 p = s2[i];
                v = (unsigned int)f2bf(p.x) | ((unsigned int)f2bf(p.y) << 16);
            }
            dstx[i] = v;
        }
        tok_cur = tokens[xb * 512 + 1];
        const float2* s2n = (const float2*)(emb + (size_t)tok_cur * 300);
#pragma unroll
        for (int k = 0; k < 10; ++k) {
            int i = xln + 16 * k;
            if (i < 150) xp[k] = s2n[i];
        }
        tok_nxt = tokens[xb * 512 + 2];
    }
    __syncthreads();   // x_0 staged in xb_lds[0]

    for (int t = 0; t < 512; ++t) {
        // ---- A. ih-MFMAs from x parity buffer (h-independent) ----
        f32x4 acc0 = {0.f, 0.f, 0.f, 0.f};
        f32x4 acc1 = {0.f, 0.f, 0.f, 0.f};
        {
            const ushort_t* u0 = xb_lds + (t & 1) * XHALF + lm * XSTRIDE + 8 * q;
            const ushort_t* u1 = u0 + 16 * XSTRIDE;
#pragma unroll
            for (int kc = 0; kc < 10; ++kc) {
                bf16x8 b0 = __builtin_bit_cast(bf16x8, *(const u16x8v*)(u0 + 32 * kc));
                bf16x8 b1 = __builtin_bit_cast(bf16x8, *(const u16x8v*)(u1 + 32 * kc));
                acc0 = __builtin_amdgcn_mfma_f32_16x16x32_bf16(aih[kc], b0, acc0, 0, 0, 0);
                acc1 = __builtin_amdgcn_mfma_f32_16x16x32_bf16(aih[kc], b1, acc1, 0, 0, 0);
            }
        }

        // ---- C. consume xp -> other x parity buffer (disjoint from A's reads) ----
        {
            unsigned int* dstx = (unsigned int*)(xb_lds + ((t + 1) & 1) * XHALF + xr * XSTRIDE);
            const bool tz = (tok_cur != 0);
#pragma unroll
            for (int k = 0; k < 10; ++k) {
                int i = xln + 16 * k;
                unsigned int v = 0u;
                if (tz && i < 150)
                    v = (unsigned int)f2bf(xp[k].x) | ((unsigned int)f2bf(xp[k].y) << 16);
                dstx[i] = v;
            }
        }

        // ---- wave 0 polls the 128 padded flags (monotonic; poison<0 safe) ----
        if (wv == 0) {
            const int target = t + 1;
            const int* p0 = fb + (2 * lane) * FSTR;
            const int* p1 = fb + (2 * lane + 1) * FSTR;
            while (true) {
                int v0 = g_load_flag(p0);
                int v1 = g_load_flag(p1);
                if (__all(v0 >= target && v1 >= target)) break;
                __builtin_amdgcn_s_sleep(1);
            }
            asm volatile("" ::: "memory");
        }
        __syncthreads();   // S2a: release; also orders C-writes vs next A-reads

        // ---- stage h_t: coalesced bypassing u64 loads -> h_lds (R4/R9 law) ----
        {
            const u64_t* hsrc = (const u64_t*)(hbuf + (size_t)(t & 1) * (256 * 512)
                                               + (size_t)xb * 512);
            u64_t* dsth = (u64_t*)(h_lds + xr * HSTRIDE);
            u64_t tmp[8];
#pragma unroll
            for (int k = 0; k < 8; ++k) tmp[k] = g_load64(hsrc + xln + 16 * k);
#pragma unroll
            for (int k = 0; k < 8; ++k) dsth[xln + 16 * k] = tmp[k];
        }
        __syncthreads();   // S2b: h staged

        // ---- hh-MFMAs ----
        {
            const ushort_t* v0 = h_lds + lm * HSTRIDE + 8 * q;
            const ushort_t* v1 = v0 + 16 * HSTRIDE;
#pragma unroll
            for (int kc = 0; kc < 16; ++kc) {
                bf16x8 b0 = __builtin_bit_cast(bf16x8, *(const u16x8v*)(v0 + 32 * kc));
                bf16x8 b1 = __builtin_bit_cast(bf16x8, *(const u16x8v*)(v1 + 32 * kc));
                acc0 = __builtin_amdgcn_mfma_f32_16x16x32_bf16(ahh[kc], b0, acc0, 0, 0, 0);
                acc1 = __builtin_amdgcn_mfma_f32_16x16x32_bf16(ahh[kc], b1, acc1, 0, 0, 0);
            }
        }

        // ---- elementwise LSTM + shfl-pack + per-wave store + drain + publish ----
        {
            float ig = sigmoidf_(acc0.x + bias0);
            float fg = sigmoidf_(acc0.y + bias1);
            float gg = tanhf_(acc0.z + bias2);
            float og = sigmoidf_(acc0.w + bias3);
            cA = fg * cA + ig * gg;
            unsigned pA = f2bf(og * tanhf_(cA));

            ig = sigmoidf_(acc1.x + bias0);
            fg = sigmoidf_(acc1.y + bias1);
            gg = tanhf_(acc1.z + bias2);
            og = sigmoidf_(acc1.w + bias3);
            cB = fg * cB + ig * gg;
            unsigned pB = f2bf(og * tanhf_(cB));

            unsigned a0 = (unsigned)__shfl((int)pA, lm);
            unsigned a1 = (unsigned)__shfl((int)pA, lm + 16);
            unsigned a2 = (unsigned)__shfl((int)pA, lm + 32);
            unsigned a3 = (unsigned)__shfl((int)pA, lm + 48);
            unsigned b0 = (unsigned)__shfl((int)pB, lm);
            unsigned b1 = (unsigned)__shfl((int)pB, lm + 16);
            unsigned b2 = (unsigned)__shfl((int)pB, lm + 32);
            unsigned b3 = (unsigned)__shfl((int)pB, lm + 48);
            u64_t uA = (u64_t)(a0 | (a1 << 16)) | ((u64_t)(a2 | (a3 << 16)) << 32);
            u64_t uB = (u64_t)(b0 | (b1 << 16)) | ((u64_t)(b2 | (b3 << 16)) << 32);

            ushort_t* hdst = hbuf + (size_t)((t + 1) & 1) * (256 * 512);
            if (q == 0)
                g_store64((u64_t*)(hdst + (size_t)(Bg0 + lm) * 512 + U0 + 4 * wv), uA);
            else if (q == 1)
                g_store64((u64_t*)(hdst + (size_t)(Bg0 + 16 + lm) * 512 + U0 + 4 * wv), uB);
        }
        asm volatile("s_waitcnt vmcnt(0)" ::: "memory");   // own h stores at LLC
        if (lane == 0) g_store_flag(mypub, t + 2);

        // ---- G. issue x prefetch for t+2 (after drain: stays in flight) ----
        {
            tok_cur = tok_nxt;
            const float2* s2 = (const float2*)(emb + (size_t)tok_cur * 300);
#pragma unroll
            for (int k = 0; k < 10; ++k) {
                int i = xln + 16 * k;
                if (i < 150) xp[k] = s2[i];
            }
            int t3 = (t + 3 < 512) ? (t + 3) : 511;
            tok_nxt = tokens[xb * 512 + t3];
        }
        // no loop-end barrier: A(t+1) reads parity written at C(t), ordered by S2a/S2b
    }

    // ---- epilogue: wave0 waits group done (513), then FC ----
    if (wv == 0) {
        const int* p0 = fb + (2 * lane) * FSTR;
        const int* p1 = fb + (2 * lane + 1) * FSTR;
        while (true) {
            int v0 = g_load_flag(p0);
            int v1 = g_load_flag(p1);
            if (__all(v0 >= 513 && v1 >= 513)) break;
            __builtin_amdgcn_s_sleep(1);
        }
        asm volatile("" ::: "memory");
    }
    __syncthreads();

    {
        const int bb = Bg0 + 2 * ib + (wv & 1);
        const int obase = wv >> 1;                       // 0..3
        const ushort_t* hrow = hbuf + (size_t)bb * 512;  // final h in parity 0
        u64_t h0 = g_load64((const u64_t*)(hrow + lane * 8));
        u64_t h1 = g_load64((const u64_t*)(hrow + lane * 8 + 4));
        float hv[8];
#pragma unroll
        for (int j = 0; j < 4; ++j) hv[j]     = bf2f((ushort_t)(h0 >> (16 * j)));
#pragma unroll
        for (int j = 0; j < 4; ++j) hv[4 + j] = bf2f((ushort_t)(h1 >> (16 * j)));
#pragma unroll
        for (int oo = 0; oo < 2; ++oo) {
            int o = obase + oo * 4;
            if (o < 7) {
                f32x4 w0 = *(const f32x4*)(Wfc + o * 512 + lane * 8);
                f32x4 w1 = *(const f32x4*)(Wfc + o * 512 + lane * 8 + 4);
                float s = hv[0] * w0.x + hv[1] * w0.y + hv[2] * w0.z + hv[3] * w0.w
                        + hv[4] * w1.x + hv[5] * w1.y + hv[6] * w1.z + hv[7] * w1.w;
#pragma unroll
                for (int sh = 32; sh >= 1; sh >>= 1) s += __shfl_down(s, sh);
                if (lane == 0)
                    out[bb * 7 + o] = s + bfc[o];
            }
        }
    }
}

extern "C" void kernel_launch(void* const* d_in, const int* in_sizes, int n_in,
                              void* d_out, int out_size, void* d_ws, size_t ws_size,
                              hipStream_t stream) {
    const int* tokens = (const int*)d_in[0];
    const float* emb  = (const float*)d_in[1];
    const float* Wih  = (const float*)d_in[2];
    const float* bih  = (const float*)d_in[3];
    const float* Whh  = (const float*)d_in[4];
    const float* bhh  = (const float*)d_in[5];
    const float* Wfc  = (const float*)d_in[6];
    const float* bfc  = (const float*)d_in[7];

    int* flags      = (int*)d_ws;                        // 1024 flags x 64B = 64 KiB
    ushort_t* hbuf  = (ushort_t*)((char*)d_ws + 65536);  // [2][256][512] bf16 = 512 KiB

    lstm_fused_kernel<<<dim3(128), dim3(512), 0, stream>>>(
        tokens, emb, Wih, bih, Whh, bhh, Wfc, bfc,
        (float*)d_out, flags, hbuf);
}